// Round 2
// baseline (476.216 us; speedup 1.0000x reference)
//
#include <hip/hip_runtime.h>
#include <cstdint>
#include <cstddef>

// Problem constants (reference: M=8192, IN=4096, OUT=4096)
#define M_DIM 8192
#define K_DIM 4096
#define N_DIM 4096

typedef unsigned short u16;
typedef __bf16 bf16x8 __attribute__((ext_vector_type(8)));
typedef u16 u16x8 __attribute__((ext_vector_type(8)));
typedef float f32x4 __attribute__((ext_vector_type(4)));

// fp32 -> bf16 round-to-nearest-even (inputs are finite normals; no NaN path)
__device__ __forceinline__ u16 f2bf_rne(float f) {
  uint32_t u = __builtin_bit_cast(uint32_t, f);
  return (u16)((u + 0x7FFFu + ((u >> 16) & 1u)) >> 16);
}
// small int -> bf16 (exact for |i| <= 8)
__device__ __forceinline__ u16 i2bf(int i) {
  return (u16)(__builtin_bit_cast(uint32_t, (float)i) >> 16);
}

#define XBLKS 16384  // M*K/8/256 blocks for the x-conversion half
#define WBLKS 8192   // N*(K/2)/4/256 blocks for the weight-dequant half

// ---- Fused prep: x fp32->bf16 and packed-int4 -> bf16 integer weights ----
// Block-uniform branch (no divergence). Scale stays deferred to GEMM epilogue
// so weight values in LDS/MFMA are exact small integers.
__global__ __launch_bounds__(256) void prep(const float* __restrict__ x,
                                            const int* __restrict__ wp,
                                            u16* __restrict__ xb,
                                            u16* __restrict__ wb) {
  const int b = blockIdx.x;
  if (b < XBLKS) {
    size_t t = (size_t)b * 256 + threadIdx.x;
    const float4* xp = (const float4*)x;
    float4 a = xp[2 * t];
    float4 c = xp[2 * t + 1];
    u16x8 r;
    r[0] = f2bf_rne(a.x); r[1] = f2bf_rne(a.y); r[2] = f2bf_rne(a.z); r[3] = f2bf_rne(a.w);
    r[4] = f2bf_rne(c.x); r[5] = f2bf_rne(c.y); r[6] = f2bf_rne(c.z); r[7] = f2bf_rne(c.w);
    ((u16x8*)xb)[t] = r;
  } else {
    size_t t = (size_t)(b - XBLKS) * 256 + threadIdx.x;
    int4 p = ((const int4*)wp)[t];
    u16x8 r;
    int v;
    v = p.x ^ 0x88; r[0] = i2bf((v << 28) >> 28); r[1] = i2bf((v << 24) >> 28);
    v = p.y ^ 0x88; r[2] = i2bf((v << 28) >> 28); r[3] = i2bf((v << 24) >> 28);
    v = p.z ^ 0x88; r[4] = i2bf((v << 28) >> 28); r[5] = i2bf((v << 24) >> 28);
    v = p.w ^ 0x88; r[6] = i2bf((v << 28) >> 28); r[7] = i2bf((v << 24) >> 28);
    ((u16x8*)wb)[t] = r;
  }
}

// ------------- bf16 gemm_bt: 256x256 tile, dbuf LDS, prefetch pipeline ------
// C[m][n] = (sum_k A[m][k]*B[n][k]) * scale[n] + bias[n]
//
// Structure upgrade from the 128x128 / 2-barrier-per-K-step version:
//   * BM=BN=256, BK=64, 512 threads = 8 waves in 2(M) x 4(N); each wave owns
//     a 128x64 output tile = 8x4 frags of mfma_f32_16x16x32_bf16 (64 MFMA
//     per wave per K-tile vs 24 ds_read_b128 -> 2.67 MFMA/read).
//   * Double-buffered LDS (2 x 32 KiB per matrix = 128 KiB total). Tile t+1's
//     8 global_load_lds are issued BEFORE computing tile t, so the single
//     boundary __syncthreads() (vmcnt(0) drain) is covered by ~600 cycles of
//     MFMA. One barrier per K-tile instead of two full drains.
//   * Buffer indices are compile-time (2x-unrolled main loop) so alias
//     analysis can see stage writes and ds_reads touch different buffers.
//
// Swizzle (unchanged, verified: SQ_LDS_BANK_CONFLICT == 0): LDS row stride is
// 64 u16 = 128 B = exactly 32 banks. Thread tid stages global 16B-chunk
// ((tid&7) ^ (row&7)) into linear LDS slot tid&7, readers address slot
// c ^ (row&7). global_load_lds requires the linear dest (rule 21).
__global__ __launch_bounds__(512, 2) void gemm_bt_w4a16(
    const u16* __restrict__ A,      // [M_DIM, K_DIM] bf16 bits
    const u16* __restrict__ B,      // [N_DIM, K_DIM] bf16 bits (integer weights)
    const float* __restrict__ scales,
    const float* __restrict__ bias,
    float* __restrict__ C) {
  __shared__ u16 sA[2][256 * 64];  // 2 x 32 KiB
  __shared__ u16 sB[2][256 * 64];  // 2 x 32 KiB

  const int tid = threadIdx.x;
  const int lane = tid & 63;
  const int wave = tid >> 6;          // 0..7
  const int m0 = blockIdx.y * 256;
  const int n0 = blockIdx.x * 256;
  const int wm = (wave >> 2) * 128;   // 0 or 128
  const int wn = (wave & 3) * 64;     // 0,64,128,192
  const int lrow = lane & 15;         // m (A) or n (B) within a 16x16 frag
  const int quad = lane >> 4;         // k-chunk selector; m-subrow for C/D

  f32x4 acc[8][4] = {};

  // Staging map: thread tid covers row (tid>>3) within a 64-row round, chunk
  // slot tid&7 (linear for global_load_lds); the global source chunk is
  // XOR-swizzled by row&7. Rounds step rows by 64 (== 0 mod 8), so the key
  // is invariant across rounds.
  const int srow = tid >> 3;                    // 0..63
  const int schunk = ((tid & 7) ^ (srow & 7)) * 8;
  const u16* ga = A + (size_t)(m0 + srow) * K_DIM + schunk;
  const u16* gb = B + (size_t)(n0 + srow) * K_DIM + schunk;
  const int ldsoff = wave * 1024;               // this wave's 8-row slab (8*128B)

  // Stage one 256x64 K-tile of A and B into buffer `buf` (8 loads/thread).
  auto stage = [&](int buf, int kb) {
#pragma unroll
    for (int r = 0; r < 4; ++r)
      __builtin_amdgcn_global_load_lds(
          (const __attribute__((address_space(1))) void*)(ga + (size_t)(r * 64) * K_DIM + kb),
          (__attribute__((address_space(3))) void*)((char*)sA[buf] + r * 8192 + ldsoff),
          16, 0, 0);
#pragma unroll
    for (int r = 0; r < 4; ++r)
      __builtin_amdgcn_global_load_lds(
          (const __attribute__((address_space(1))) void*)(gb + (size_t)(r * 64) * K_DIM + kb),
          (__attribute__((address_space(3))) void*)((char*)sB[buf] + r * 8192 + ldsoff),
          16, 0, 0);
  };

  // Compute one K-tile (64) from buffer `buf`: 2 k-slices x (12 reads + 32 MFMA).
  auto compute = [&](int buf) {
    const u16* bA = sA[buf];
    const u16* bB = sB[buf];
#pragma unroll
    for (int s = 0; s < 2; ++s) {
      const int kc = ((s * 4 + quad) ^ (lrow & 7)) * 8;
      u16x8 af[8], bfr[4];
#pragma unroll
      for (int i = 0; i < 8; ++i)
        af[i] = *(const u16x8*)(bA + (wm + i * 16 + lrow) * 64 + kc);
#pragma unroll
      for (int j = 0; j < 4; ++j)
        bfr[j] = *(const u16x8*)(bB + (wn + j * 16 + lrow) * 64 + kc);
      __builtin_amdgcn_s_setprio(1);
#pragma unroll
      for (int i = 0; i < 8; ++i)
#pragma unroll
        for (int j = 0; j < 4; ++j)
          acc[i][j] = __builtin_amdgcn_mfma_f32_16x16x32_bf16(
              __builtin_bit_cast(bf16x8, af[i]),
              __builtin_bit_cast(bf16x8, bfr[j]), acc[i][j], 0, 0, 0);
      __builtin_amdgcn_s_setprio(0);
    }
  };

  stage(0, 0);
  __syncthreads();  // vmcnt(0) drain: tile 0 resident

#pragma unroll 1
  for (int it = 0; it < 32; ++it) {
    const int kb = it * 128;
    stage(1, kb + 64);        // prefetch next tile while computing current
    compute(0);               // tile kb from buf0
    __syncthreads();          // drains stage(1) loads; buf0 readers done
    if (it < 31) stage(0, kb + 128);
    compute(1);               // tile kb+64 from buf1
    __syncthreads();
  }

  // Epilogue: C/D layout col = lane&15 (n), row = quad*4 + reg (m). Apply
  // per-output-row scale + bias here (keeps MFMA inputs exact integers).
#pragma unroll
  for (int j = 0; j < 4; ++j) {
    const int n = n0 + wn + j * 16 + lrow;
    const float sc = scales[n];
    const float bi = bias[n];
#pragma unroll
    for (int i = 0; i < 8; ++i) {
      const int m = m0 + wm + i * 16 + quad * 4;
      float* cp = &C[(size_t)m * N_DIM + n];
#pragma unroll
      for (int r = 0; r < 4; ++r)
        cp[(size_t)r * N_DIM] = acc[i][j][r] * sc + bi;
    }
  }
}

// ---------------- Fallback (ws too small): fp32 direct, correct but slow ----
__global__ __launch_bounds__(256) void fallback_w4a16(
    const float* __restrict__ x, const int* __restrict__ wp,
    const float* __restrict__ scales, const float* __restrict__ bias,
    float* __restrict__ out) {
  const int n = blockIdx.x * 256 + threadIdx.x;
  const int m = blockIdx.y;
  const float* xr = x + (size_t)m * K_DIM;
  const int* wr = wp + (size_t)n * (K_DIM / 2);
  float acc = 0.f;
  for (int j = 0; j < K_DIM / 2; ++j) {
    int w = wr[j] ^ 0x88;
    float lo = (float)((w << 28) >> 28);
    float hi = (float)((w << 24) >> 28);
    acc += xr[2 * j] * lo + xr[2 * j + 1] * hi;
  }
  out[(size_t)m * N_DIM + n] = acc * scales[n] + bias[n];
}

extern "C" void kernel_launch(void* const* d_in, const int* in_sizes, int n_in,
                              void* d_out, int out_size, void* d_ws, size_t ws_size,
                              hipStream_t stream) {
  const float* x = (const float*)d_in[0];
  const int* wp = (const int*)d_in[1];
  const float* sc = (const float*)d_in[2];
  const float* bi = (const float*)d_in[3];
  float* out = (float*)d_out;

  const size_t xb_elems = (size_t)M_DIM * K_DIM;           // 33.55M u16 = 64 MiB
  const size_t wb_elems = (size_t)N_DIM * K_DIM;           // 16.78M u16 = 32 MiB
  const size_t need = (xb_elems + wb_elems) * sizeof(u16); // 100,663,296 B

  if (ws_size >= need) {
    u16* xb = (u16*)d_ws;
    u16* wb = xb + xb_elems;
    prep<<<XBLKS + WBLKS, 256, 0, stream>>>(x, wp, xb, wb);
    gemm_bt_w4a16<<<dim3(N_DIM / 256, M_DIM / 256), 512, 0, stream>>>(xb, wb, sc, bi, out);
  } else {
    fallback_w4a16<<<dim3(N_DIM / 256, M_DIM), 256, 0, stream>>>(x, wp, sc, bi, out);
  }
}